// Round 7
// baseline (12637.633 us; speedup 1.0000x reference)
//
#include <hip/hip_runtime.h>
#include <hip/hip_bf16.h>

#define B_   64
#define S_   512
#define I_   512
#define H_   1024
#define G4H  4096
#define O_   512
#define CH_  32    // timesteps per chunk
#define NCH  (S_ / CH_)   // 16 chunks per layer

#define NBLK   128        // chunk_k grid: 64 blocks/layer (16 hidden units each)
#define THR_   512        // threads per chunk_k block (8 waves)
#define NGRP   8          // row-group readiness counters per step (8 batches each)
#define BARSTR 32         // uints per counter (128B, own cacheline)

typedef short s16x8 __attribute__((ext_vector_type(8)));
typedef short s16x4 __attribute__((ext_vector_type(4)));
typedef float f32x4 __attribute__((ext_vector_type(4)));
typedef unsigned long long u64;
using bf16 = __hip_bfloat16;

__device__ __forceinline__ float bf2f(bf16 v) { return __bfloat162float(v); }
__device__ __forceinline__ bf16  f2bf(float f) { return __float2bfloat16(f); }
__device__ __forceinline__ short f2bfb(float f) { bf16 h = __float2bfloat16(f); return *(short*)&h; }

__device__ __forceinline__ void storeC(float* p, float v) { *p = v; }
__device__ __forceinline__ void storeC(bf16* p, float v)  { *p = f2bf(v); }

// ---------------------------------------------------------------------------
// C = A @ Bw^T (+bias1+bias2). Bw fp32 global (bf16-converted while staging).
// Tile 128x128, BK=32, 256 threads (4 waves, 64x64 quadrant each).
// ---------------------------------------------------------------------------
template <int AMAP, int CMAP, int ABF, typename CT>
__global__ __launch_bounds__(256) void gemm_bt(
    const void* __restrict__ Av, const float* __restrict__ Bw,
    CT* __restrict__ C,
    const float* __restrict__ bias1, const float* __restrict__ bias2,
    int M, int N, int K, int t0)
{
    __shared__ bf16 As[128 * 40];
    __shared__ bf16 Bs[128 * 40];

    const int tid  = threadIdx.x;
    const int wave = tid >> 6;
    const int lane = tid & 63;
    const int quad = lane >> 4;
    const int l16  = lane & 15;

    const int m_base = blockIdx.x * 128;
    const int n_base = blockIdx.y * 128;
    const int wm = (wave >> 1) * 64;
    const int wn = (wave & 1) * 64;

    f32x4 acc[4][4] = {};

    for (int k0 = 0; k0 < K; k0 += 32) {
        __syncthreads();
#pragma unroll
        for (int i = 0; i < 2; i++) {
            int l   = tid + i * 256;     // 0..511
            int row = l >> 2;            // 0..127
            int ko  = (l & 3) * 8;       // 0,8,16,24
            int m   = m_base + row;
            long ar = m;
            if (AMAP == 1) ar = (long)(m & 63) * S_ + t0 + (m >> 6);

            if (ABF) {
                const bf16* ap = (const bf16*)Av + ar * (long)K + k0 + ko;
                *(s16x8*)(&As[row * 40 + ko]) = *(const s16x8*)ap;
            } else {
                const float* ap = (const float*)Av + ar * (long)K + k0 + ko;
                f32x4 a0 = *(const f32x4*)ap;
                f32x4 a1 = *(const f32x4*)(ap + 4);
                s16x8 av;
#pragma unroll
                for (int j = 0; j < 4; j++) { av[j] = f2bfb(a0[j]); av[4 + j] = f2bfb(a1[j]); }
                *(s16x8*)(&As[row * 40 + ko]) = av;
            }

            const float* bp = &Bw[(long)(n_base + row) * K + k0 + ko];
            f32x4 b0 = *(const f32x4*)bp;
            f32x4 b1 = *(const f32x4*)(bp + 4);
            s16x8 bv;
#pragma unroll
            for (int j = 0; j < 4; j++) { bv[j] = f2bfb(b0[j]); bv[4 + j] = f2bfb(b1[j]); }
            *(s16x8*)(&Bs[row * 40 + ko]) = bv;
        }
        __syncthreads();

        s16x8 af[4], bfr[4];
#pragma unroll
        for (int i = 0; i < 4; i++)
            af[i] = *(const s16x8*)(&As[(wm + i * 16 + l16) * 40 + quad * 8]);
#pragma unroll
        for (int j = 0; j < 4; j++)
            bfr[j] = *(const s16x8*)(&Bs[(wn + j * 16 + l16) * 40 + quad * 8]);
#pragma unroll
        for (int i = 0; i < 4; i++)
#pragma unroll
            for (int j = 0; j < 4; j++)
                acc[i][j] = __builtin_amdgcn_mfma_f32_16x16x32_bf16(af[i], bfr[j], acc[i][j], 0, 0, 0);
    }

    // C/D layout: col = lane&15, row = (lane>>4)*4 + reg
#pragma unroll
    for (int i = 0; i < 4; i++) {
#pragma unroll
        for (int j = 0; j < 4; j++) {
#pragma unroll
            for (int r = 0; r < 4; r++) {
                int m = m_base + wm + i * 16 + quad * 4 + r;
                int n = n_base + wn + j * 16 + l16;
                float v = acc[i][j][r];
                if (bias1) v += bias1[n];
                if (bias2) v += bias2[n];
                long cr = m;
                if (CMAP == 2) cr = (long)(m & 63) * S_ + t0 + (m >> 6);
                storeC(&C[cr * (long)N + n], v);
            }
        }
    }
}

// ---------------------------------------------------------------------------
// Persistent per-chunk recurrence with PER-ROW-GROUP DATAFLOW sync (no global
// barrier). 128 blocks: [0,64) layer 0 (iff do0), [64,128) layer 1 (iff do1);
// inactive blocks return. Each block owns 16 hidden units = 64 gate-cols;
// Whh slice (64x1024) bf16 in LDS once per chunk.
//
// 8 waves = (cw, mw): wave computes batches mw*16+l16 (16 rows), cols
// cw*32..+32 (2 frags), FULL K=1024 (32 MFMA-pairs) -> accumulator is final,
// no K-merge phase. Per step only 2 __syncthreads (gs-ready, gs-WAR).
//
// Readiness: 8 monotonic counters per (layer, step) — one per row-group of 8
// batches. Producers flush h in two halves (rep0 = batches 0..31, rep1 =
// 32..63): stores -> s_waitcnt vmcnt(0) -> one RMW per wave to the group's
// counter (2 waves x 64 blocks = 128 arrivals/ctr). Consumers poll ONLY the
// 2 counters covering their rows. sc1 (agent-scope relaxed) loads/stores keep
// everything at the coherent point; LLC serializes stores < RMW < poll < load.
// Counters reused across the 17 launches via target = 128 * (#activations).
// Fast blocks stream ahead per row-group instead of waiting on a global max.
// ---------------------------------------------------------------------------
__global__ __launch_bounds__(THR_, 1) void chunk_k(
    const bf16* __restrict__ xg0,  // [CH][B][4H] layer-0 input contrib, chunk cpar
    const bf16* __restrict__ xg1,  // [CH][B][4H] layer-1 input contrib, chunk cpar-1
    const float* __restrict__ Whh0,
    const float* __restrict__ Whh1,
    bf16* __restrict__ h0w,        // [2][CH+1][B][H] double-buffered window
    bf16* __restrict__ h1w,        // [CH+1][B][H]
    float* __restrict__ c0,
    float* __restrict__ c1,
    unsigned* __restrict__ bar,    // [2][CH-1][NGRP][BARSTR], zeroed once, reused
    int cpar, int do0, int do1)
{
    const int layer  = blockIdx.x >> 6;
    const int nb     = blockIdx.x & 63;
    const int active = layer ? do1 : do0;   // block-uniform
    if (!active) return;

    const bf16*  xg  = layer ? xg1  : xg0;
    const float* Whh = layer ? Whh1 : Whh0;
    float*       cst = layer ? c1   : c0;

    bf16 *rbuf, *cbuf;
    if (layer == 0) {
        rbuf = h0w + (size_t)(cpar & 1) * (CH_ + 1) * B_ * H_;
        cbuf = h0w + (size_t)((cpar + 1) & 1) * (CH_ + 1) * B_ * H_;
    } else {
        rbuf = h1w; cbuf = h1w;
    }

    const int tid  = threadIdx.x;
    const int lane = tid & 63;
    const int wave = tid >> 6;     // 0..7
    const int quad = lane >> 4;
    const int l16  = lane & 15;
    const int cw   = wave & 1;     // col-half (32 gate-cols)
    const int mw   = wave >> 1;    // row-group (batches mw*16 .. +16)

    // per-layer counter region + monotonic reuse target (128 per activation)
    unsigned* barL = bar + (size_t)layer * (CH_ - 1) * NGRP * BARSTR;
    const unsigned bar_tgt = (layer ? (unsigned)cpar : (unsigned)(cpar + 1)) * 128u;

    __shared__ bf16  wsh[64][1032];   // 132.1 KB; +8 pad: 2-way aliasing only
    __shared__ float gs[64][68];      // 17.4 KB; [batch][gate-col]

    // stage Whh slice (64 gate-rows x 1024) fp32 -> bf16 LDS, ONCE per chunk.
    // wsh row r: gate g = r>>4, unit uu = r&15 -> Whh row g*H + nb*16 + uu
    {
        int r  = tid >> 3;                 // 0..63
        int cc = (tid & 7) * 128;          // 128 elems per thread
        const float* src = Whh + ((long)(r >> 4) * H_ + nb * 16 + (r & 15)) * H_ + cc;
#pragma unroll
        for (int q = 0; q < 128; q += 4) {
            f32x4 v = *(const f32x4*)(src + q);
            s16x4 o;
#pragma unroll
            for (int w = 0; w < 4; w++) o[w] = f2bfb(v[w]);
            *(s16x4*)(&wsh[r][cc + q]) = o;
        }
    }
    __syncthreads();

    // epilogue cell ownership: cell = tid + rep*512, bb = cell>>4, uu = cell&15
    const int uu   = tid & 15;
    const int unit = nb * 16 + uu;
    float creg[2];
#pragma unroll
    for (int rep = 0; rep < 2; rep++) {
        int bb = (tid + rep * 512) >> 4;
        creg[rep] = cst[(long)bb * H_ + unit];
    }

    // prologue: xg prefetch for j=0
    float xn[2][4];
#pragma unroll
    for (int rep = 0; rep < 2; rep++) {
        int bb = (tid + rep * 512) >> 4;
#pragma unroll
        for (int g = 0; g < 4; g++)
            xn[rep][g] = bf2f(xg[(long)bb * G4H + (long)g * H_ + unit]);
    }

    for (int j = 0; j < CH_; j++) {
        // ---- wait for the 2 row-groups this wave consumes (j=0: boundary) ----
        if (j > 0) {
            unsigned* cj = barL + (size_t)(j - 1) * NGRP * BARSTR;
            while (__hip_atomic_load(cj + (2 * mw) * BARSTR, __ATOMIC_RELAXED,
                                     __HIP_MEMORY_SCOPE_AGENT) < bar_tgt)
                __builtin_amdgcn_s_sleep(1);
            while (__hip_atomic_load(cj + (2 * mw + 1) * BARSTR, __ATOMIC_RELAXED,
                                     __HIP_MEMORY_SCOPE_AGENT) < bar_tgt)
                __builtin_amdgcn_s_sleep(1);
            __builtin_amdgcn_sched_barrier(0);
            asm volatile("" ::: "memory");
        }

        // ---- full-K MFMA: rows mw*16+l16, cols cw*32..+32 ----
        const u64* ap = (const u64*)(rbuf + (long)j * (B_ * H_)
                       + (long)(mw * 16 + l16) * H_) + quad * 2;
        u64 la[32], lb[32];
#pragma unroll
        for (int t = 0; t < 32; t++) {
            u64* p = (u64*)(ap + (size_t)t * 8);
            la[t] = __hip_atomic_load(p,     __ATOMIC_RELAXED, __HIP_MEMORY_SCOPE_AGENT);
            lb[t] = __hip_atomic_load(p + 1, __ATOMIC_RELAXED, __HIP_MEMORY_SCOPE_AGENT);
        }

        f32x4 acc0 = {}, acc1 = {};
#pragma unroll
        for (int t = 0; t < 32; t++) {
            union { u64 q[2]; s16x8 v; } ua;
            ua.q[0] = la[t]; ua.q[1] = lb[t];
            int k = t * 32;
            s16x8 b0 = *(const s16x8*)(&wsh[(2 * cw + 0) * 16 + l16][k + quad * 8]);
            s16x8 b1 = *(const s16x8*)(&wsh[(2 * cw + 1) * 16 + l16][k + quad * 8]);
            acc0 = __builtin_amdgcn_mfma_f32_16x16x32_bf16(ua.v, b0, acc0, 0, 0, 0);
            acc1 = __builtin_amdgcn_mfma_f32_16x16x32_bf16(ua.v, b1, acc1, 0, 0, 0);
        }

        // C layout: col = frag*16 + l16, row = mw*16 + quad*4 + r  (final, no merge)
#pragma unroll
        for (int r = 0; r < 4; r++) {
            int m = mw * 16 + quad * 4 + r;
            gs[m][(2 * cw + 0) * 16 + l16] = acc0[r];
            gs[m][(2 * cw + 1) * 16 + l16] = acc1[r];
        }
        __syncthreads();   // SYNC1: gs ready for epilogue

        // ---- epilogue with SPLIT FLUSH: rep0 (bb 0..31) then rep1 (32..63) ----
#pragma unroll
        for (int rep = 0; rep < 2; rep++) {
            int bb = (tid + rep * 512) >> 4;
            float gi = gs[bb][uu]      + xn[rep][0];
            float gf = gs[bb][16 + uu] + xn[rep][1];
            float gg = gs[bb][32 + uu] + xn[rep][2];
            float go = gs[bb][48 + uu] + xn[rep][3];

            float ig = 1.f / (1.f + __expf(-gi));
            float fg = 1.f / (1.f + __expf(-gf));
            float og = 1.f / (1.f + __expf(-go));
            float e2 = __expf(-2.f * fabsf(gg));
            float tg = (1.f - e2) / (1.f + e2);
            tg = (gg < 0.f) ? -tg : tg;

            creg[rep] = fg * creg[rep] + ig * tg;
            float e2c = __expf(-2.f * fabsf(creg[rep]));
            float tc = (1.f - e2c) / (1.f + e2c);
            tc = (creg[rep] < 0.f) ? -tc : tc;

            bf16 hv = f2bf(og * tc);
            unsigned my    = *(unsigned short*)&hv;
            unsigned other = (unsigned)__shfl((int)my, lane ^ 1, 64);
            if (!(uu & 1)) {
                unsigned v32 = my | (other << 16);
                unsigned* dst = (unsigned*)(rbuf + (long)(j + 1) * (B_ * H_)
                                + (long)bb * H_ + unit);
                __hip_atomic_store(dst, v32, __ATOMIC_RELAXED, __HIP_MEMORY_SCOPE_AGENT);
                if (j == CH_ - 1) {
                    unsigned* cd = (unsigned*)(cbuf + (long)bb * H_ + unit);
                    __hip_atomic_store(cd, v32, __ATOMIC_RELAXED, __HIP_MEMORY_SCOPE_AGENT);
                }
            }
            // drain this wave's stores to the coherent point, then publish.
            // wave w's rep-half covers batches of row-group (rep*4 + (w>>1)).
            asm volatile("s_waitcnt vmcnt(0)" ::: "memory");
            if (j < CH_ - 1 && lane == 0)
                __hip_atomic_fetch_add(
                    barL + ((size_t)j * NGRP + rep * 4 + (wave >> 1)) * BARSTR, 1u,
                    __ATOMIC_RELAXED, __HIP_MEMORY_SCOPE_AGENT);
        }

        // prefetch next step's xg (launch-constant)
        if (j + 1 < CH_) {
            const bf16* xq = xg + (long)(j + 1) * (B_ * G4H);
#pragma unroll
            for (int rep = 0; rep < 2; rep++) {
                int bb = (tid + rep * 512) >> 4;
#pragma unroll
                for (int g = 0; g < 4; g++)
                    xn[rep][g] = bf2f(xq[(long)bb * G4H + (long)g * H_ + unit]);
            }
        }

        __syncthreads();   // SYNC2: all gs reads done before next step's write
    }

#pragma unroll
    for (int rep = 0; rep < 2; rep++) {
        int bb = (tid + rep * 512) >> 4;
        cst[(long)bb * H_ + unit] = creg[rep];
    }
}

// zero c-states, carry-in h slots, and readiness counters
__global__ __launch_bounds__(256) void init_k(
    float* c0, float* c1, bf16* h0w, bf16* h1w, unsigned* bar, int nbar)
{
    int i = blockIdx.x * 256 + threadIdx.x;
    if (i < B_ * H_) {
        c0[i] = 0.f; c1[i] = 0.f;
        h0w[i] = f2bf(0.f);   // buf 0, slot 0
        h1w[i] = f2bf(0.f);   // slot 0
    }
    if (i < nbar) bar[i] = 0u;
}

// h_n: layer0 = h0w buf0 slot0 (final carry), layer1 = h1w slot0. c_n fp32.
__global__ __launch_bounds__(256) void finalize_k(
    const bf16* __restrict__ h0w, const bf16* __restrict__ h1w,
    const float* __restrict__ c0, const float* __restrict__ c1,
    float* __restrict__ out_hn, float* __restrict__ out_cn)
{
    int i = blockIdx.x * 256 + threadIdx.x;
    if (i < B_ * H_) {
        out_hn[i]            = bf2f(h0w[i]);
        out_hn[B_ * H_ + i]  = bf2f(h1w[i]);
        out_cn[i]            = c0[i];
        out_cn[B_ * H_ + i]  = c1[i];
    }
}

extern "C" void kernel_launch(void* const* d_in, const int* in_sizes, int n_in,
                              void* d_out, int out_size, void* d_ws, size_t ws_size,
                              hipStream_t stream)
{
    const float* x    = (const float*)d_in[0];
    const float* Wih0 = (const float*)d_in[1];
    const float* Whh0 = (const float*)d_in[2];
    const float* bih0 = (const float*)d_in[3];
    const float* bhh0 = (const float*)d_in[4];
    const float* Wih1 = (const float*)d_in[5];
    const float* Whh1 = (const float*)d_in[6];
    const float* bih1 = (const float*)d_in[7];
    const float* bhh1 = (const float*)d_in[8];
    const float* Wfc  = (const float*)d_in[9];
    const float* bfc  = (const float*)d_in[10];
    float* out = (float*)d_out;

    // workspace (~45.2 MB total — identical envelope to rounds 1/2/4/5/6)
    char* p = (char*)d_ws;
    float* c0  = (float*)p; p += (size_t)B_ * H_ * 4;                       // 256 KB
    float* c1  = (float*)p; p += (size_t)B_ * H_ * 4;                       // 256 KB
    bf16* h0w  = (bf16*)p;  p += (size_t)2 * (CH_ + 1) * B_ * H_ * 2;       // 8.25 MB
    bf16* h1w  = (bf16*)p;  p += (size_t)(CH_ + 1) * B_ * H_ * 2;           // 4.13 MB
    bf16* xg0  = (bf16*)p;  p += (size_t)CH_ * B_ * G4H * 2;                // 16 MB
    bf16* xg1  = (bf16*)p;  p += (size_t)CH_ * B_ * G4H * 2;                // 16 MB
    unsigned* bar = (unsigned*)p;
    const int nbar = 2 * (CH_ - 1) * NGRP * BARSTR;                         // 62 KB, reused
    p += (size_t)nbar * 4;

    init_k<<<(B_ * H_ + 255) / 256, 256, 0, stream>>>(c0, c1, h0w, h1w, bar, nbar);

    const dim3 gxg0((B_ * CH_) / 128, G4H / 128);  // 16 x 32
    const dim3 gfc((B_ * CH_) / 128, O_ / 128);    // 16 x 4

    // Diagonal pipeline over 17 groups: layer0 on chunk c, layer1 on chunk c-1.
    for (int c = 0; c <= NCH; c++) {
        const int do0 = (c < NCH);
        const int do1 = (c >= 1);

        if (do0) {
            // xg0(c): xg0[t][b] = x[b][c*CH+t] @ Wih0^T + bih0 + bhh0   (A fp32)
            gemm_bt<1, 0, 0, bf16><<<gxg0, 256, 0, stream>>>(
                x, Wih0, xg0, bih0, bhh0, B_ * CH_, G4H, I_, c * CH_);
        }
        if (do1) {
            // xg1(c-1): from h0 window buf (c-1)&1, slots 1..CH           (A bf16)
            const bf16* h0chunk = h0w + (size_t)((c - 1) & 1) * (CH_ + 1) * B_ * H_ + B_ * H_;
            gemm_bt<0, 0, 1, bf16><<<gxg0, 256, 0, stream>>>(
                h0chunk, Wih1, xg1, bih1, bhh1, B_ * CH_, G4H, H_, 0);
        }

        // one persistent cooperative launch = all CH_ steps of this group
        {
            const bf16*  a0  = xg0;  const bf16*  a1  = xg1;
            const float* w0  = Whh0; const float* w1  = Whh1;
            bf16* hp0 = h0w; bf16* hp1 = h1w;
            float* cp0 = c0; float* cp1 = c1;
            unsigned* bp = bar;
            int cv = c, d0 = do0, d1 = do1;
            void* args[] = { &a0, &a1, &w0, &w1, &hp0, &hp1,
                             &cp0, &cp1, &bp, &cv, &d0, &d1 };
            hipLaunchCooperativeKernel((const void*)chunk_k,
                                       dim3(NBLK), dim3(THR_), args, 0, stream);
        }

        if (do1) {
            // FC on layer-1 chunk c-1: out rows t0=(c-1)*CH              (A bf16, C fp32)
            gemm_bt<0, 2, 1, float><<<gfc, 256, 0, stream>>>(
                h1w + B_ * H_, Wfc, out, bfc, (const float*)nullptr,
                B_ * CH_, O_, H_, (c - 1) * CH_);
        }
    }

    finalize_k<<<(B_ * H_ + 255) / 256, 256, 0, stream>>>(
        h0w, h1w, c0, c1,
        out + (size_t)B_ * S_ * O_,
        out + (size_t)B_ * S_ * O_ + 2 * (size_t)B_ * H_);
}

// Round 8
// 6682.811 us; speedup vs baseline: 1.8911x; 1.8911x over previous
//
#include <hip/hip_runtime.h>
#include <hip/hip_bf16.h>

#define B_   64
#define S_   512
#define I_   512
#define H_   1024
#define G4H  4096
#define O_   512
#define CH_  16           // timesteps per chunk (halved: fits double-buffers in envelope)
#define NCH  (S_ / CH_)   // 32 chunks per layer

#define LSTR   8          // barrier stripes per layer
#define BARSTR 32         // uints per stripe (128B, own cacheline)
#define HWSZ   ((CH_ + 1) * B_ * H_)   // elems per h-window buffer
#define XGSZ   (CH_ * B_ * G4H)        // elems per xg buffer

typedef short s16x8 __attribute__((ext_vector_type(8)));
typedef short s16x4 __attribute__((ext_vector_type(4)));
typedef float f32x4 __attribute__((ext_vector_type(4)));
typedef unsigned long long u64;
using bf16 = __hip_bfloat16;

__device__ __forceinline__ float bf2f(bf16 v) { return __bfloat162float(v); }
__device__ __forceinline__ bf16  f2bf(float f) { return __float2bfloat16(f); }
__device__ __forceinline__ short f2bfb(float f) { bf16 h = __float2bfloat16(f); return *(short*)&h; }

__device__ __forceinline__ void storeC(float* p, float v) { *p = v; }
__device__ __forceinline__ void storeC(bf16* p, float v)  { *p = f2bf(v); }

// ---------------------------------------------------------------------------
// Standalone 256-thr GEMM (prologue xg0(0) + epilogue FC(31)). Proven body.
// ---------------------------------------------------------------------------
template <int AMAP, int CMAP, int ABF, typename CT>
__global__ __launch_bounds__(256) void gemm_bt(
    const void* __restrict__ Av, const float* __restrict__ Bw,
    CT* __restrict__ C,
    const float* __restrict__ bias1, const float* __restrict__ bias2,
    int M, int N, int K, int t0)
{
    __shared__ bf16 As[128 * 40];
    __shared__ bf16 Bs[128 * 40];

    const int tid  = threadIdx.x;
    const int wave = tid >> 6;
    const int lane = tid & 63;
    const int quad = lane >> 4;
    const int l16  = lane & 15;

    const int m_base = blockIdx.x * 128;
    const int n_base = blockIdx.y * 128;
    const int wm = (wave >> 1) * 64;
    const int wn = (wave & 1) * 64;

    f32x4 acc[4][4] = {};

    for (int k0 = 0; k0 < K; k0 += 32) {
        __syncthreads();
#pragma unroll
        for (int i = 0; i < 2; i++) {
            int l   = tid + i * 256;
            int row = l >> 2;
            int ko  = (l & 3) * 8;
            int m   = m_base + row;
            long ar = m;
            if (AMAP == 1) ar = (long)(m & 63) * S_ + t0 + (m >> 6);

            if (ABF) {
                const bf16* ap = (const bf16*)Av + ar * (long)K + k0 + ko;
                *(s16x8*)(&As[row * 40 + ko]) = *(const s16x8*)ap;
            } else {
                const float* ap = (const float*)Av + ar * (long)K + k0 + ko;
                f32x4 a0 = *(const f32x4*)ap;
                f32x4 a1 = *(const f32x4*)(ap + 4);
                s16x8 av;
#pragma unroll
                for (int j = 0; j < 4; j++) { av[j] = f2bfb(a0[j]); av[4 + j] = f2bfb(a1[j]); }
                *(s16x8*)(&As[row * 40 + ko]) = av;
            }

            const float* bp = &Bw[(long)(n_base + row) * K + k0 + ko];
            f32x4 b0 = *(const f32x4*)bp;
            f32x4 b1 = *(const f32x4*)(bp + 4);
            s16x8 bv;
#pragma unroll
            for (int j = 0; j < 4; j++) { bv[j] = f2bfb(b0[j]); bv[4 + j] = f2bfb(b1[j]); }
            *(s16x8*)(&Bs[row * 40 + ko]) = bv;
        }
        __syncthreads();

        s16x8 af[4], bfr[4];
#pragma unroll
        for (int i = 0; i < 4; i++)
            af[i] = *(const s16x8*)(&As[(wm + i * 16 + l16) * 40 + quad * 8]);
#pragma unroll
        for (int j = 0; j < 4; j++)
            bfr[j] = *(const s16x8*)(&Bs[(wn + j * 16 + l16) * 40 + quad * 8]);
#pragma unroll
        for (int i = 0; i < 4; i++)
#pragma unroll
            for (int j = 0; j < 4; j++)
                acc[i][j] = __builtin_amdgcn_mfma_f32_16x16x32_bf16(af[i], bfr[j], acc[i][j], 0, 0, 0);
    }

#pragma unroll
    for (int i = 0; i < 4; i++)
#pragma unroll
        for (int j = 0; j < 4; j++)
#pragma unroll
            for (int r = 0; r < 4; r++) {
                int m = m_base + wm + i * 16 + quad * 4 + r;
                int n = n_base + wn + j * 16 + l16;
                float v = acc[i][j][r];
                if (bias1) v += bias1[n];
                if (bias2) v += bias2[n];
                long cr = m;
                if (CMAP == 2) cr = (long)(m & 63) * S_ + t0 + (m >> 6);
                storeC(&C[cr * (long)N + n], v);
            }
}

// ---------------------------------------------------------------------------
// 512-thread 128x128 GEMM tile (runtime-parameterized) for aux blocks.
// 8 waves: wm=(w>>2)*64, wn=(w&3)*32 -> acc[4][2]. Reuses block smem.
// ---------------------------------------------------------------------------
__device__ void gemm_tile(const void* Av, const float* Bw, void* Cv,
                          const float* bias1, const float* bias2,
                          int N, int K, int t0, int amap, int cmap,
                          int abf, int cbf, int tx, int ty, char* smem)
{
    bf16* As = (bf16*)smem;                    // [128*40]
    bf16* Bs = (bf16*)(smem + 128 * 40 * 2);   // [128*40]

    const int tid  = threadIdx.x;
    const int wave = tid >> 6;
    const int lane = tid & 63;
    const int quad = lane >> 4;
    const int l16  = lane & 15;
    const int m_base = tx * 128;
    const int n_base = ty * 128;
    const int wm = (wave >> 2) * 64;
    const int wn = (wave & 3) * 32;

    f32x4 acc[4][2] = {};

    for (int k0 = 0; k0 < K; k0 += 32) {
        __syncthreads();
        {
            int l   = tid;            // 0..511 (one pass)
            int row = l >> 2;
            int ko  = (l & 3) * 8;
            int m   = m_base + row;
            long ar = m;
            if (amap == 1) ar = (long)(m & 63) * S_ + t0 + (m >> 6);

            if (abf) {
                const bf16* ap = (const bf16*)Av + ar * (long)K + k0 + ko;
                *(s16x8*)(&As[row * 40 + ko]) = *(const s16x8*)ap;
            } else {
                const float* ap = (const float*)Av + ar * (long)K + k0 + ko;
                f32x4 a0 = *(const f32x4*)ap;
                f32x4 a1 = *(const f32x4*)(ap + 4);
                s16x8 av;
#pragma unroll
                for (int j = 0; j < 4; j++) { av[j] = f2bfb(a0[j]); av[4 + j] = f2bfb(a1[j]); }
                *(s16x8*)(&As[row * 40 + ko]) = av;
            }
            const float* bp = &Bw[(long)(n_base + row) * K + k0 + ko];
            f32x4 b0 = *(const f32x4*)bp;
            f32x4 b1 = *(const f32x4*)(bp + 4);
            s16x8 bv;
#pragma unroll
            for (int j = 0; j < 4; j++) { bv[j] = f2bfb(b0[j]); bv[4 + j] = f2bfb(b1[j]); }
            *(s16x8*)(&Bs[row * 40 + ko]) = bv;
        }
        __syncthreads();

        s16x8 af[4], bfr[2];
#pragma unroll
        for (int i = 0; i < 4; i++)
            af[i] = *(const s16x8*)(&As[(wm + i * 16 + l16) * 40 + quad * 8]);
#pragma unroll
        for (int j = 0; j < 2; j++)
            bfr[j] = *(const s16x8*)(&Bs[(wn + j * 16 + l16) * 40 + quad * 8]);
#pragma unroll
        for (int i = 0; i < 4; i++)
#pragma unroll
            for (int j = 0; j < 2; j++)
                acc[i][j] = __builtin_amdgcn_mfma_f32_16x16x32_bf16(af[i], bfr[j], acc[i][j], 0, 0, 0);
    }

#pragma unroll
    for (int i = 0; i < 4; i++)
#pragma unroll
        for (int j = 0; j < 2; j++)
#pragma unroll
            for (int r = 0; r < 4; r++) {
                int m = m_base + wm + i * 16 + quad * 4 + r;
                int n = n_base + wn + j * 16 + l16;
                float v = acc[i][j][r];
                if (bias1) v += bias1[n];
                if (bias2) v += bias2[n];
                long cr = m;
                if (cmap == 2) cr = (long)(m & 63) * S_ + t0 + (m >> 6);
                if (cbf) storeC((bf16*)Cv + cr * (long)N + n, v);
                else     storeC((float*)Cv + cr * (long)N + n, v);
            }
}

// ---------------------------------------------------------------------------
// Per-layer striped fence-free barrier (R6-proven). 64 arrivals/layer over
// 8 stripes; wave-0 lanes 0..7 poll; monotonic counters reused across
// launches via per-layer activation-count targets.
// ---------------------------------------------------------------------------
__device__ __forceinline__ void grid_bar(unsigned* ctr, unsigned target)
{
    __syncthreads();
    const int t = threadIdx.x;
    if (t == 0)
        __hip_atomic_fetch_add(ctr + ((blockIdx.x & 63) & (LSTR - 1)) * BARSTR, 1u,
                               __ATOMIC_RELAXED, __HIP_MEMORY_SCOPE_AGENT);
    if (t < LSTR) {
        while (__hip_atomic_load(ctr + t * BARSTR, __ATOMIC_RELAXED,
                                 __HIP_MEMORY_SCOPE_AGENT) < target)
            __builtin_amdgcn_s_sleep(1);
    }
    __syncthreads();
}

// ---------------------------------------------------------------------------
// FUSED persistent launch, 256 blocks x 512 thr (1 block/CU, 149.5 KB LDS):
//   blocks [0,64):    layer-0 recurrence, chunk cpar       (iff do0)
//   blocks [64,128):  layer-1 recurrence, chunk cpar-2     (iff do1)
//   blocks [128,256): aux GEMMs, all chunk-grained independent:
//       xg0(cpar+1)  [reads x]
//       xg1(cpar-1)  [reads h0 window written LAST launch]
//       FC (cpar-3)  [reads h1 window written LAST launch]
// Recurrence step structure = R6 verbatim (K-half waves, two-phase LDS merge,
// striped per-layer barrier, sc1 h-atomics, all-upfront loads, xg prefetch).
// Buffer parities (all verified disjoint within a launch):
//   h0w: rec writes buf cpar&1 (+carry slot0 of other buf); aux reads other
//        buf slots 1..CH. xg0: rec reads cpar&1, aux writes other. h1w: rec
//        writes cpar&1, aux FC reads other buf slots 1..CH. xg1: rec reads
//        cpar&1, aux writes other.
// ---------------------------------------------------------------------------
__global__ __launch_bounds__(512, 1) void fused_k(
    const float* __restrict__ x,
    const float* __restrict__ Wih0, const float* __restrict__ Wih1,
    const float* __restrict__ Wfc,
    const float* __restrict__ bih0, const float* __restrict__ bhh0,
    const float* __restrict__ bih1, const float* __restrict__ bhh1,
    const float* __restrict__ bfc,
    const float* __restrict__ Whh0, const float* __restrict__ Whh1,
    bf16* __restrict__ h0w, bf16* __restrict__ h1w,
    bf16* __restrict__ xg0, bf16* __restrict__ xg1,
    float* __restrict__ c0, float* __restrict__ c1,
    float* __restrict__ out,
    unsigned* __restrict__ bar, int cpar, int do0, int do1)
{
    __shared__ __align__(16) char smem[149504];   // wsh 132096B + gs 17408B

    // ---------------- aux GEMM blocks ----------------
    if (blockIdx.x >= 128) {
        const int a = blockIdx.x - 128;
        const int n_xg0 = (cpar <= NCH - 2) ? 256 : 0;               // xg0(cpar+1)
        const int n_xg1 = (cpar >= 1 && cpar <= NCH) ? 256 : 0;      // xg1(cpar-1)
        const int n_fc  = (cpar >= 3) ? 32 : 0;                      // FC(cpar-3)
        const int ntot  = n_xg0 + n_xg1 + n_fc;
        for (int idx = a; idx < ntot; idx += 128) {
            if (idx < n_xg0) {
                int tx = idx & 7, ty = idx >> 3;
                gemm_tile(x, Wih0, xg0 + (size_t)((cpar + 1) & 1) * XGSZ,
                          bih0, bhh0, G4H, I_, (cpar + 1) * CH_,
                          1, 0, 0, 1, tx, ty, smem);
            } else if (idx < n_xg0 + n_xg1) {
                int k = idx - n_xg0, tx = k & 7, ty = k >> 3;
                gemm_tile(h0w + (size_t)((cpar - 1) & 1) * HWSZ + B_ * H_, Wih1,
                          xg1 + (size_t)((cpar - 1) & 1) * XGSZ,
                          bih1, bhh1, G4H, H_, 0,
                          0, 0, 1, 1, tx, ty, smem);
            } else {
                int k = idx - n_xg0 - n_xg1, tx = k & 7, ty = k >> 3;
                gemm_tile(h1w + (size_t)((cpar - 3) & 1) * HWSZ + B_ * H_, Wfc,
                          out, bfc, (const float*)nullptr, O_, H_, (cpar - 3) * CH_,
                          0, 2, 1, 0, tx, ty, smem);
            }
        }
        return;
    }

    // ---------------- recurrence blocks (R6 structure) ----------------
    const int layer  = blockIdx.x >> 6;
    const int nb     = blockIdx.x & 63;
    const int active = layer ? do1 : do0;
    if (!active) return;

    const bf16*  xg  = layer ? (xg1 + (size_t)(cpar & 1) * XGSZ)    // chunk cpar-2
                             : (xg0 + (size_t)(cpar & 1) * XGSZ);   // chunk cpar
    const float* Whh = layer ? Whh1 : Whh0;
    float*       cst = layer ? c1   : c0;

    bf16* hwb = layer ? h1w : h0w;
    bf16* rbuf = hwb + (size_t)(cpar & 1) * HWSZ;           // both layers: parity cpar&1
    bf16* cbuf = hwb + (size_t)((cpar + 1) & 1) * HWSZ;     // carry -> other buf slot 0

    const int tid  = threadIdx.x;
    const int lane = tid & 63;
    const int wave = tid >> 6;     // 0..7
    const int quad = lane >> 4;
    const int l16  = lane & 15;
    const int kw   = wave >> 2;    // K-half
    const int mw   = wave & 3;     // row-group

    unsigned* barL = bar + (size_t)layer * (CH_ - 1) * LSTR * BARSTR;
    const unsigned bar_tgt =
        (layer ? (unsigned)(cpar - 1) : (unsigned)(cpar + 1)) * (64 / LSTR);

    bf16*  wsh = (bf16*)smem;                  // [64][1032]
    float* gs  = (float*)(smem + 132096);      // [64][68]

    // stage Whh slice (64 gate-rows x 1024) fp32 -> bf16 LDS, once per chunk
    {
        int r  = tid >> 3;                 // 0..63
        int cc = (tid & 7) * 128;
        const float* src = Whh + ((long)(r >> 4) * H_ + nb * 16 + (r & 15)) * H_ + cc;
#pragma unroll
        for (int q = 0; q < 128; q += 4) {
            f32x4 v = *(const f32x4*)(src + q);
            s16x4 o;
#pragma unroll
            for (int w = 0; w < 4; w++) o[w] = f2bfb(v[w]);
            *(s16x4*)(&wsh[r * 1032 + cc + q]) = o;
        }
    }
    __syncthreads();

    const int uu   = tid & 15;
    const int unit = nb * 16 + uu;
    float creg[2];
#pragma unroll
    for (int rep = 0; rep < 2; rep++) {
        int bb = (tid + rep * 512) >> 4;
        creg[rep] = cst[(long)bb * H_ + unit];
    }

    float xn[2][4];
#pragma unroll
    for (int rep = 0; rep < 2; rep++) {
        int bb = (tid + rep * 512) >> 4;
#pragma unroll
        for (int g = 0; g < 4; g++)
            xn[rep][g] = bf2f(xg[(long)bb * G4H + (long)g * H_ + unit]);
    }

    for (int j = 0; j < CH_; j++) {
        // ---- MFMA: rows mw*16+l16, K-half kw, all 64 gate-cols ----
        const u64* ap = (const u64*)(rbuf + (long)j * (B_ * H_)
                       + (long)(mw * 16 + l16) * H_ + kw * 512) + quad * 2;
        u64 la[16], lb[16];
#pragma unroll
        for (int t = 0; t < 16; t++) {
            u64* p = (u64*)(ap + (size_t)t * 8);
            la[t] = __hip_atomic_load(p,     __ATOMIC_RELAXED, __HIP_MEMORY_SCOPE_AGENT);
            lb[t] = __hip_atomic_load(p + 1, __ATOMIC_RELAXED, __HIP_MEMORY_SCOPE_AGENT);
        }

        f32x4 acc[4] = {};
#pragma unroll
        for (int t = 0; t < 16; t++) {
            union { u64 q[2]; s16x8 v; } ua;
            ua.q[0] = la[t]; ua.q[1] = lb[t];
            int k = kw * 512 + t * 32;
#pragma unroll
            for (int cf = 0; cf < 4; cf++) {
                s16x8 b = *(const s16x8*)(&wsh[(cf * 16 + l16) * 1032 + k + quad * 8]);
                acc[cf] = __builtin_amdgcn_mfma_f32_16x16x32_bf16(ua.v, b, acc[cf], 0, 0, 0);
            }
        }

        // ---- two-phase K-half merge in gs ----
        if (kw == 0) {
#pragma unroll
            for (int cf = 0; cf < 4; cf++)
#pragma unroll
                for (int r = 0; r < 4; r++)
                    gs[(mw * 16 + quad * 4 + r) * 68 + cf * 16 + l16] = acc[cf][r];
        }
        __syncthreads();
        if (kw == 1) {
#pragma unroll
            for (int cf = 0; cf < 4; cf++)
#pragma unroll
                for (int r = 0; r < 4; r++)
                    gs[(mw * 16 + quad * 4 + r) * 68 + cf * 16 + l16] += acc[cf][r];
        }
        __syncthreads();

        // ---- epilogue ----
        unsigned short hb[2];
#pragma unroll
        for (int rep = 0; rep < 2; rep++) {
            int bb = (tid + rep * 512) >> 4;
            float gi = gs[bb * 68 + uu]      + xn[rep][0];
            float gf = gs[bb * 68 + 16 + uu] + xn[rep][1];
            float gg = gs[bb * 68 + 32 + uu] + xn[rep][2];
            float go = gs[bb * 68 + 48 + uu] + xn[rep][3];

            float ig = 1.f / (1.f + __expf(-gi));
            float fg = 1.f / (1.f + __expf(-gf));
            float og = 1.f / (1.f + __expf(-go));
            float e2 = __expf(-2.f * fabsf(gg));
            float tg = (1.f - e2) / (1.f + e2);
            tg = (gg < 0.f) ? -tg : tg;

            creg[rep] = fg * creg[rep] + ig * tg;
            float e2c = __expf(-2.f * fabsf(creg[rep]));
            float tc = (1.f - e2c) / (1.f + e2c);
            tc = (creg[rep] < 0.f) ? -tc : tc;

            bf16 hv = f2bf(og * tc);
            hb[rep] = *(unsigned short*)&hv;
        }
#pragma unroll
        for (int rep = 0; rep < 2; rep++) {
            int bb = (tid + rep * 512) >> 4;
            unsigned my    = hb[rep];
            unsigned other = (unsigned)__shfl((int)my, lane ^ 1, 64);
            if (!(uu & 1)) {
                unsigned v32 = my | (other << 16);
                unsigned* dst = (unsigned*)(rbuf + (long)(j + 1) * (B_ * H_)
                                + (long)bb * H_ + unit);
                __hip_atomic_store(dst, v32, __ATOMIC_RELAXED, __HIP_MEMORY_SCOPE_AGENT);
                if (j == CH_ - 1) {
                    unsigned* cd = (unsigned*)(cbuf + (long)bb * H_ + unit);
                    __hip_atomic_store(cd, v32, __ATOMIC_RELAXED, __HIP_MEMORY_SCOPE_AGENT);
                }
            }
        }

        if (j + 1 < CH_) {
            const bf16* xq = xg + (long)(j + 1) * (B_ * G4H);
#pragma unroll
            for (int rep = 0; rep < 2; rep++) {
                int bb = (tid + rep * 512) >> 4;
#pragma unroll
                for (int g = 0; g < 4; g++)
                    xn[rep][g] = bf2f(xq[(long)bb * G4H + (long)g * H_ + unit]);
            }
        }

        if (j < CH_ - 1)
            grid_bar(barL + (size_t)j * LSTR * BARSTR, bar_tgt);
    }

#pragma unroll
    for (int rep = 0; rep < 2; rep++) {
        int bb = (tid + rep * 512) >> 4;
        cst[(long)bb * H_ + unit] = creg[rep];
    }
}

// zero c-states, carry-in h slots (buf 0 slot 0 of each window), counters
__global__ __launch_bounds__(256) void init_k(
    float* c0, float* c1, bf16* h0w, bf16* h1w, unsigned* bar, int nbar)
{
    int i = blockIdx.x * 256 + threadIdx.x;
    if (i < B_ * H_) {
        c0[i] = 0.f; c1[i] = 0.f;
        h0w[i] = f2bf(0.f);
        h1w[i] = f2bf(0.f);
    }
    if (i < nbar) bar[i] = 0u;
}

// h_n: layer0 carry = h0w buf0 slot0; layer1 carry = h1w buf0 slot0.
__global__ __launch_bounds__(256) void finalize_k(
    const bf16* __restrict__ h0w, const bf16* __restrict__ h1w,
    const float* __restrict__ c0, const float* __restrict__ c1,
    float* __restrict__ out_hn, float* __restrict__ out_cn)
{
    int i = blockIdx.x * 256 + threadIdx.x;
    if (i < B_ * H_) {
        out_hn[i]            = bf2f(h0w[i]);
        out_hn[B_ * H_ + i]  = bf2f(h1w[i]);
        out_cn[i]            = c0[i];
        out_cn[B_ * H_ + i]  = c1[i];
    }
}

extern "C" void kernel_launch(void* const* d_in, const int* in_sizes, int n_in,
                              void* d_out, int out_size, void* d_ws, size_t ws_size,
                              hipStream_t stream)
{
    const float* x    = (const float*)d_in[0];
    const float* Wih0 = (const float*)d_in[1];
    const float* Whh0 = (const float*)d_in[2];
    const float* bih0 = (const float*)d_in[3];
    const float* bhh0 = (const float*)d_in[4];
    const float* Wih1 = (const float*)d_in[5];
    const float* Whh1 = (const float*)d_in[6];
    const float* bih1 = (const float*)d_in[7];
    const float* bhh1 = (const float*)d_in[8];
    const float* Wfc  = (const float*)d_in[9];
    const float* bfc  = (const float*)d_in[10];
    float* out = (float*)d_out;

    // workspace ~41.4 MB (< proven 45.2 MB envelope)
    char* p = (char*)d_ws;
    float* c0  = (float*)p; p += (size_t)B_ * H_ * 4;                 // 256 KB
    float* c1  = (float*)p; p += (size_t)B_ * H_ * 4;                 // 256 KB
    bf16* h0w  = (bf16*)p;  p += (size_t)2 * HWSZ * 2;                // 4.46 MB
    bf16* h1w  = (bf16*)p;  p += (size_t)2 * HWSZ * 2;                // 4.46 MB
    bf16* xg0  = (bf16*)p;  p += (size_t)2 * XGSZ * 2;                // 16 MB
    bf16* xg1  = (bf16*)p;  p += (size_t)2 * XGSZ * 2;                // 16 MB
    unsigned* bar = (unsigned*)p;
    const int nbar = 2 * (CH_ - 1) * LSTR * BARSTR;                   // 30 KB
    p += (size_t)nbar * 4;

    init_k<<<(B_ * H_ + 255) / 256, 256, 0, stream>>>(c0, c1, h0w, h1w, bar, nbar);

    // prologue: xg0(0) into buf 0
    {
        dim3 g((B_ * CH_) / 128, G4H / 128);   // 8 x 32
        gemm_bt<1, 0, 0, bf16><<<g, 256, 0, stream>>>(
            x, Wih0, xg0, bih0, bhh0, B_ * CH_, G4H, I_, 0);
    }

    // 2-deep diagonal: launch c runs layer0(chunk c), layer1(chunk c-2),
    // aux {xg0(c+1), xg1(c-1), FC(c-3)}.
    for (int c = 0; c <= NCH + 1; c++) {
        int d0 = (c <= NCH - 1);
        int d1 = (c >= 2);
        const float* xa = x;
        const float* wi0 = Wih0; const float* wi1 = Wih1; const float* wfc = Wfc;
        const float* b0i = bih0; const float* b0h = bhh0;
        const float* b1i = bih1; const float* b1h = bhh1; const float* bf_ = bfc;
        const float* wh0 = Whh0; const float* wh1 = Whh1;
        bf16* hp0 = h0w; bf16* hp1 = h1w; bf16* xp0 = xg0; bf16* xp1 = xg1;
        float* cp0 = c0; float* cp1 = c1; float* op = out;
        unsigned* bp = bar; int cv = c;
        void* args[] = { &xa, &wi0, &wi1, &wfc, &b0i, &b0h, &b1i, &b1h, &bf_,
                         &wh0, &wh1, &hp0, &hp1, &xp0, &xp1, &cp0, &cp1, &op,
                         &bp, &cv, &d0, &d1 };
        hipLaunchCooperativeKernel((const void*)fused_k,
                                   dim3(256), dim3(512), args, 0, stream);
    }

    // epilogue: FC(NCH-1) (h1 window buf (NCH-1)&1, written in launch NCH+1)
    {
        dim3 g((B_ * CH_) / 128, O_ / 128);    // 8 x 4
        gemm_bt<0, 2, 1, float><<<g, 256, 0, stream>>>(
            h1w + (size_t)((NCH - 1) & 1) * HWSZ + B_ * H_, Wfc, out, bfc,
            (const float*)nullptr, B_ * CH_, O_, H_, (NCH - 1) * CH_);
    }

    finalize_k<<<(B_ * H_ + 255) / 256, 256, 0, stream>>>(
        h0w, h1w, c0, c1,
        out + (size_t)B_ * S_ * O_,
        out + (size_t)B_ * S_ * O_ + 2 * (size_t)B_ * H_);
}